// Round 10
// baseline (996.984 us; speedup 1.0000x reference)
//
#include <hip/hip_runtime.h>

// ---------------------------------------------------------------------------
// Earth-specific transformer block (Pangu/swin style) for MI355X gfx950.
// DIM=192, HEADS=6 (d=32), RES=(8,96,180), WIN=(2,6,12), SHIFT=(1,3,6), MLP=4x
// All GEMMs in bf16 MFMA (16x16x32), fp32 accumulate. Output fp32.
// R10: GEMM reverted to R7-exact (BK=64 A+B global_load_lds staging, 28KB,
//      launch_bounds(256,4) — R9's A-in-registers variant regressed via
//      occupancy + coalescing). attn Q-CHUNKED: S/P tile 48 rows (3 chunks),
//      LDS 50->28KB -> 5 blocks/CU; both bias slices staged up-front;
//      O stored per chunk as full 128B lines. exp2-domain softmax kept.
// ---------------------------------------------------------------------------

typedef __attribute__((ext_vector_type(8))) short short8;
typedef __attribute__((ext_vector_type(4))) short short4v;
typedef __attribute__((ext_vector_type(4))) float floatx4;
typedef unsigned short bfu;   // raw bf16 bits

#define GLOAD_LDS16(g, l)                                            \
  __builtin_amdgcn_global_load_lds(                                  \
      (const __attribute__((address_space(1))) unsigned int*)(g),    \
      (__attribute__((address_space(3))) unsigned int*)(l), 16, 0, 0)

__device__ __forceinline__ bfu f2bf(float f) {
  unsigned int u = __builtin_bit_cast(unsigned int, f);
  u += 0x7fffu + ((u >> 16) & 1u);        // round-to-nearest-even
  return (bfu)(u >> 16);
}
__device__ __forceinline__ float bf2f(bfu s) {
  return __builtin_bit_cast(float, (unsigned int)s << 16);
}

// --- transpose fp32 (K x N) -> bf16 (N x K) --------------------------------
__global__ void wt_kernel(const float* __restrict__ src, bfu* __restrict__ dst,
                          int K, int N) {
  int idx = blockIdx.x * 256 + threadIdx.x;
  if (idx >= K * N) return;
  int k = idx / N, n = idx % N;
  dst[(size_t)n * K + k] = f2bf(src[idx]);
}

// --- compact bias: tblT[h][w][3312] bf16 from table[ep][w][h] fp32 ---------
// Scaled by 1/ln2: softmax computed in exp2 domain.
__global__ void bias2_kernel(const float* __restrict__ table,
                             bfu* __restrict__ out) {
  int idx = blockIdx.x * 256 + threadIdx.x;
  if (idx >= 1271808) return;                    // 6*64*3312
  int h = idx / 211968;
  int r = idx % 211968;
  int w = r / 3312, ep = r % 3312;
  out[idx] = f2bf(table[(size_t)ep * 384 + w * 6 + h] * 1.4426950408889634f);
}

// --- zero the m=144..159 pad columns of the transposed V buffer ------------
__global__ void vpad_kernel(unsigned int* __restrict__ vbw) {
  int tid = threadIdx.x;
  int dd = tid >> 3, c = tid & 7;
  vbw[(size_t)blockIdx.x * 2560 + dd * 80 + 72 + c] = 0;
}

// --- LN1 + roll(-shift) + window-partition gather -> bf16 A1 ---------------
__global__ __launch_bounds__(256) void ln1_kernel(
    const float* __restrict__ x, const float* __restrict__ g,
    const float* __restrict__ be, bfu* __restrict__ A1) {
  int wv = threadIdx.x >> 6, lane = threadIdx.x & 63;
  int r = blockIdx.x * 4 + wv;
  int n = r % 144, w = (r / 144) & 63, bb = r / 9216;
  int ip = w >> 4, il = w & 15;
  int p1 = n / 72, rem = n % 72, l1 = rem / 12, o1 = rem % 12;
  int pl = ip * 2 + p1 + 1;   if (pl >= 8) pl -= 8;     // rolled pos + shift
  int lat = il * 6 + l1 + 3;  if (lat >= 96) lat -= 96;
  int lon = bb * 12 + o1 + 6; if (lon >= 180) lon -= 180;
  size_t t = (size_t)(pl * 96 + lat) * 180 + lon;
  const float* xr = x + t * 192;
  float v0 = xr[lane], v1 = xr[lane + 64], v2 = xr[lane + 128];
  float s = v0 + v1 + v2;
  #pragma unroll
  for (int o = 32; o; o >>= 1) s += __shfl_xor(s, o);
  float mu = s * (1.0f / 192.0f);
  float d0 = v0 - mu, d1 = v1 - mu, d2 = v2 - mu;
  float q2 = d0 * d0 + d1 * d1 + d2 * d2;
  #pragma unroll
  for (int o = 32; o; o >>= 1) q2 += __shfl_xor(q2, o);
  float rstd = rsqrtf(q2 * (1.0f / 192.0f) + 1e-5f);
  bfu* orow = A1 + (size_t)r * 192;
  orow[lane]       = f2bf(d0 * rstd * g[lane]       + be[lane]);
  orow[lane + 64]  = f2bf(d1 * rstd * g[lane + 64]  + be[lane + 64]);
  orow[lane + 128] = f2bf(d2 * rstd * g[lane + 128] + be[lane + 128]);
}

// --- LN2 (natural rows) -> bf16 --------------------------------------------
__global__ __launch_bounds__(256) void ln2_kernel(
    const float* __restrict__ xin, const float* __restrict__ g,
    const float* __restrict__ be, bfu* __restrict__ yout) {
  int wv = threadIdx.x >> 6, lane = threadIdx.x & 63;
  size_t r = (size_t)blockIdx.x * 4 + wv;
  const float* xr = xin + r * 192;
  float v0 = xr[lane], v1 = xr[lane + 64], v2 = xr[lane + 128];
  float s = v0 + v1 + v2;
  #pragma unroll
  for (int o = 32; o; o >>= 1) s += __shfl_xor(s, o);
  float mu = s * (1.0f / 192.0f);
  float d0 = v0 - mu, d1 = v1 - mu, d2 = v2 - mu;
  float q2 = d0 * d0 + d1 * d1 + d2 * d2;
  #pragma unroll
  for (int o = 32; o; o >>= 1) q2 += __shfl_xor(q2, o);
  float rstd = rsqrtf(q2 * (1.0f / 192.0f) + 1e-5f);
  bfu* orow = yout + r * 192;
  orow[lane]       = f2bf(d0 * rstd * g[lane]       + be[lane]);
  orow[lane + 64]  = f2bf(d1 * rstd * g[lane + 64]  + be[lane + 64]);
  orow[lane + 128] = f2bf(d2 * rstd * g[lane + 128] + be[lane + 128]);
}

// --- MFMA GEMM: one (128-row M-panel, 96-col N-tile) per block -------------
// (R7-exact) grid = 1080*NT blocks, XCD-chunked M-major swizzle. BK=64:
// A (128x64) + B (96x64) async-staged to LDS via global_load_lds(16B),
// XOR slot swizzle, 2 barriers per chunk. LDS 28 KB.
__global__ __launch_bounds__(256, 4) void gemm_kernel(
    const bfu* __restrict__ A, const bfu* __restrict__ BT,
    const float* __restrict__ bias, int K, int NT, int mode,
    const float* aux, void* out0, void* out1, void* out2) {
  __shared__ __align__(16) short LB[14336];      // 28 KB: As[8192] + Bs[6144]
  short* As = LB;                                // [128][8 slots of 8 shorts]
  short* Bs = LB + 8192;                         // [96][8 slots]
  bfu* E = (bfu*)LB;                             // epilogue tile [128][104]
  const int tid = threadIdx.x;
  const int wv = tid >> 6, lane = tid & 63;
  const int r16 = lane & 15, quad = lane >> 4;
  const int sw = r16 & 7;                        // read-side XOR key

  const int W = gridDim.x;
  const int work = (blockIdx.x & 7) * (W >> 3) + (blockIdx.x >> 3);
  const int m0 = (work / NT) * 128;
  const int n0 = (work % NT) * 96;
  const bfu* Bsrc = BT + (size_t)n0 * K;

  floatx4 acc[2][6];
  #pragma unroll
  for (int s = 0; s < 2; ++s)
    #pragma unroll
    for (int j = 0; j < 6; ++j) acc[s][j] = (floatx4){0.f, 0.f, 0.f, 0.f};

  for (int kc = 0; kc < K; kc += 64) {
    __syncthreads();                           // prev chunk fully read
    // stage A: 1024 16B-chunks (128 rows x 8 slots), 4 per thread
    #pragma unroll
    for (int j = 0; j < 4; ++j) {
      int c = j * 256 + tid;
      int row = c >> 3, l = (c & 7) ^ (row & 7);
      GLOAD_LDS16(A + (size_t)(m0 + row) * K + kc + l * 8, As + c * 8);
    }
    // stage B: 768 16B-chunks (96 rows x 8 slots), 3 per thread
    #pragma unroll
    for (int j = 0; j < 3; ++j) {
      int c = j * 256 + tid;
      int row = c >> 3, l = (c & 7) ^ (row & 7);
      GLOAD_LDS16(Bsrc + (size_t)row * K + kc + l * 8, Bs + c * 8);
    }
    __syncthreads();                           // drains vmcnt -> data ready
    #pragma unroll
    for (int ks = 0; ks < 2; ++ks) {
      const int p8 = ((ks * 4 + quad) ^ sw) * 8;
      short8 a[2], b[6];
      #pragma unroll
      for (int s = 0; s < 2; ++s)
        a[s] = *(const short8*)(As + (wv * 32 + s * 16 + r16) * 64 + p8);
      #pragma unroll
      for (int j = 0; j < 6; ++j)
        b[j] = *(const short8*)(Bs + (j * 16 + r16) * 64 + p8);
      #pragma unroll
      for (int s = 0; s < 2; ++s)
        #pragma unroll
        for (int j = 0; j < 6; ++j)
          acc[s][j] =
              __builtin_amdgcn_mfma_f32_16x16x32_bf16(a[s], b[j], acc[s][j], 0, 0, 0);
    }
  }

  if (mode == 0 || mode == 2) {
    // ---- stage epilogue tile in LDS (bf16), then coalesced 16B stores ----
    __syncthreads();                 // all waves done reading As/Bs
    #pragma unroll
    for (int s = 0; s < 2; ++s) {
      int er = wv * 32 + s * 16 + quad * 4;
      #pragma unroll
      for (int j = 0; j < 6; ++j) {
        int c = j * 16 + r16;
        float bia = bias[n0 + c];
        #pragma unroll
        for (int i = 0; i < 4; ++i) {
          float val = acc[s][j][i] + bia;
          if (mode == 0) {
            // q pre-scale: d^-0.5 * 1/ln2 (softmax in exp2 domain)
            if (n0 < 192) val *= 0.25503633958871686f;
            E[(er + i) * 104 + c] = f2bf(val);
          } else {
            float ge = 0.5f * val * (1.0f + erff(val * 0.70710678118654752f));
            E[(er + i) * 104 + c] = f2bf(ge);
          }
        }
      }
    }
    __syncthreads();
    if (mode == 2) {
      // h[row][768], 16B chunks: 128 rows x 12 chunks = 1536
      #pragma unroll
      for (int u = 0; u < 6; ++u) {
        int id = u * 256 + tid;
        int r = id / 12, c8 = (id % 12) * 8;
        *(short8*)((bfu*)out0 + (size_t)(m0 + r) * 768 + n0 + c8) =
            *(const short8*)(E + r * 104 + c8);
      }
    } else if (n0 < 384) {
      // q or k: [win][n][32], 16B chunks along dd
      bfu* dst = (bfu*)(n0 < 192 ? out0 : out1);
      #pragma unroll
      for (int u = 0; u < 6; ++u) {
        int id = u * 256 + tid;
        int r = id / 12, c8 = (id % 12) * 8;
        int row = m0 + r;
        int n = row % 144, w = (row / 144) & 63, bb = row / 9216;
        int head = ((n0 + c8) % 192) >> 5, dd = c8 & 31;
        size_t win = (size_t)(bb * 6 + head) * 64 + w;
        *(short8*)(dst + win * 4608 + n * 32 + dd) =
            *(const short8*)(E + r * 104 + c8);
      }
    } else {
      // v transposed: [win][dd][160], 16B chunks along n (8 rows of E)
      #pragma unroll
      for (int u = 0; u < 6; ++u) {
        int id = u * 256 + tid;
        int c = id % 96, k8 = id / 96;
        int r0 = k8 * 8;
        int row0 = m0 + r0;                // multiples of 8; 144%8==0
        int n = row0 % 144, w = (row0 / 144) & 63, bb = row0 / 9216;
        int head = ((n0 + c) % 192) >> 5, dd = c & 31;
        size_t win = (size_t)(bb * 6 + head) * 64 + w;
        short8 t8;
        #pragma unroll
        for (int i = 0; i < 8; ++i) t8[i] = (short)E[(r0 + i) * 104 + c];
        *(short8*)((bfu*)out2 + win * 5120 + dd * 160 + n) = t8;
      }
    }
  } else {
    // ---- direct fp32 epilogue (modes 1 and 3): 64B quad-chunk stores ----
    #pragma unroll
    for (int s = 0; s < 2; ++s) {
      const int row0 = m0 + wv * 32 + s * 16 + quad * 4;
      #pragma unroll
      for (int j = 0; j < 6; ++j) {
        int col = n0 + j * 16 + r16;
        float bia = bias[col];
        #pragma unroll
        for (int i = 0; i < 4; ++i) {
          int row = row0 + i;
          float val = acc[s][j][i] + bia;
          if (mode == 1) {
            int n = row % 144, w = (row / 144) & 63, bb = row / 9216;
            int ip = w >> 4, il = w & 15;
            int p1 = n / 72, rem = n % 72, l1 = rem / 12, o1 = rem % 12;
            int pl = ip * 2 + p1 + 1;   if (pl >= 8) pl -= 8;
            int lat = il * 6 + l1 + 3;  if (lat >= 96) lat -= 96;
            int lon = bb * 12 + o1 + 6; if (lon >= 180) lon -= 180;
            size_t t = (size_t)(pl * 96 + lat) * 180 + lon;
            ((float*)out0)[t * 192 + col] = aux[t * 192 + col] + val;
          } else {
            size_t idx = (size_t)row * 192 + col;
            ((float*)out0)[idx] = aux[idx] + val;
          }
        }
      }
    }
  }
}

// --- windowed attention: one block per (b, head-pair, w) --------------------
// R10: Q-chunked — 3 chunks of 48 Q-rows. S/P tile [48][148] (14.2KB),
// both heads' bias slices staged up-front (13.2KB); LDS ~28.4KB -> 5
// blocks/CU. Per chunk x head: QK^T (reg-hoisted frags), exp2 softmax
// (no max pass), PV operand-swapped; O chunk staged in LDS and stored as
// full 128B lines.
__global__ __launch_bounds__(256) void attn_kernel(
    const bfu* __restrict__ qg_, const bfu* __restrict__ kg_,
    const bfu* __restrict__ vg_, const bfu* __restrict__ tblT,
    bfu* __restrict__ aout) {
  __shared__ __align__(16) bfu Ss[48 * 148];    // 14.2 KB (also O stage)
  __shared__ __align__(16) bfu bias2[2 * 3312]; // 13.2 KB, both heads
  __shared__ unsigned short rn[144];            // row bias index part
  __shared__ short cm[144];                     // col bias index part
  __shared__ unsigned char regs[144];           // shift-mask region ids

  const int w = blockIdx.x, h0 = blockIdx.y * 2, b = blockIdx.z;
  const int tid = threadIdx.x;
  const int wv = tid >> 6, lane = tid & 63, r16 = lane & 15, quad = lane >> 4;

  if (tid < 144) {
    int n = tid;
    int p1 = n / 72, rem = n % 72, l1 = rem / 12, o1 = rem % 12;
    rn[n] = (unsigned short)(828 * p1 + 23 * l1 + o1 + 11);
    cm[n] = (short)(1656 * p1 + 138 * l1 - o1);
    int ip = w >> 4, il = w & 15;
    int pl = ip * 2 + p1, lat = il * 6 + l1, lon = b * 12 + o1;
    int rp = pl < 6 ? 0 : (pl < 7 ? 1 : 2);
    int rl = lat < 90 ? 0 : (lat < 93 ? 1 : 2);
    int ro = lon < 174 ? 0 : 1;
    regs[n] = (unsigned char)(rp * 9 + rl * 3 + ro);
  }

  // async-stage bias slices for BOTH heads (828 x 16B chunks)
  #pragma unroll
  for (int j = 0; j < 4; ++j) {
    int c = j * 256 + tid;
    if (c < 828) {
      int hh = c / 414, cc = c - hh * 414;
      GLOAD_LDS16(tblT + (size_t)((h0 + hh) * 64 + w) * 3312 + cc * 8,
                  bias2 + hh * 3312 + cc * 8);
    }
  }
  __syncthreads();                 // tables visible + bias drained

  // per-lane column invariants (cols c = r16 + 16j, fixed for the block)
  short cmv[9];
  unsigned char creg[9];
  #pragma unroll
  for (int j = 0; j < 9; ++j) {
    int c = r16 + 16 * j;
    cmv[j] = cm[c];
    creg[j] = regs[c];
  }

  const size_t obase = (size_t)((b * 64 + w) * 144) * 192 + h0 * 32;
  const floatx4 z = (floatx4){0.f, 0.f, 0.f, 0.f};

  #pragma unroll
  for (int qc = 0; qc < 3; ++qc) {
    short4v ov[2][2];
    #pragma unroll
    for (int hh = 0; hh < 2; ++hh) {
      const size_t win = (size_t)((b * 6 + h0 + hh) * 64 + w);
      const bfu* qg = qg_ + win * 4608;
      const bfu* kg = kg_ + win * 4608;
      const bfu* vt = vg_ + win * 5120;

      // Phase 1: S[48][144] = Q(rows qc*48..) K^T. Frags reg-hoisted.
      short8 qf[3];
      #pragma unroll
      for (int t3 = 0; t3 < 3; ++t3)
        qf[t3] = *(const short8*)(qg + ((qc * 3 + t3) * 16 + r16) * 32 + quad * 8);
      const int tma = wv * 2, tmb = wv * 2 + 1;
      short8 kfa = *(const short8*)(kg + (tma * 16 + r16) * 32 + quad * 8);
      short8 kfb = *(const short8*)(kg + (tmb * 16 + r16) * 32 + quad * 8);
      short8 kfc = *(const short8*)(kg + (128 + r16) * 32 + quad * 8);
      #pragma unroll
      for (int tn = 0; tn < 3; ++tn) {
        int tng = qc * 3 + tn;
        bfu* srow = Ss + (tn * 16 + quad * 4) * 148;
        floatx4 d = __builtin_amdgcn_mfma_f32_16x16x32_bf16(qf[tn], kfa, z, 0, 0, 0);
        #pragma unroll
        for (int i = 0; i < 4; ++i) srow[i * 148 + tma * 16 + r16] = f2bf(d[i]);
        d = __builtin_amdgcn_mfma_f32_16x16x32_bf16(qf[tn], kfb, z, 0, 0, 0);
        #pragma unroll
        for (int i = 0; i < 4; ++i) srow[i * 148 + tmb * 16 + r16] = f2bf(d[i]);
        if ((tng & 3) == wv) {
          d = __builtin_amdgcn_mfma_f32_16x16x32_bf16(qf[tn], kfc, z, 0, 0, 0);
          #pragma unroll
          for (int i = 0; i < 4; ++i) srow[i * 148 + 128 + r16] = f2bf(d[i]);
        }
      }
      __syncthreads();   // S ready

      // Phase 2: softmax in exp2 domain, no max pass. 3 row-groups of 16.
      for (int rb = 0; rb < 3; ++rb) {
        int rrl = rb * 16 + wv * 4 + quad;          // 0..47 local
        int rrg = qc * 48 + rrl;                    // global row
        unsigned char rgn = regs[rrg];
        int rnv = rn[rrg];
        const bfu* srow = Ss + rrl * 148;
        const bfu* bl = bias2 + hh * 3312;
        float v[9];
        float sum = 0.f;
        #pragma unroll
        for (int j = 0; j < 9; ++j) {
          float s = bf2f(srow[r16 + 16 * j]) + bf2f(bl[rnv + cmv[j]]);
          s = (creg[j] != rgn) ? s - 144.26950408889634f : s;
          v[j] = exp2f(s);
          sum += v[j];
        }
        #pragma unroll
        for (int o = 8; o; o >>= 1) sum += __shfl_xor(sum, o);
        float inv = 1.0f / sum;
        bfu* wrow = Ss + rrl * 148;
        #pragma unroll
        for (int j = 0; j < 9; ++j) wrow[r16 + 16 * j] = f2bf(v[j] * inv);
      }
      __syncthreads();   // P ready

      // Phase 3: O = P V, operand-swapped; V^T B-frags hoisted.
      short8 bfr[2][5];
      #pragma unroll
      for (int td = 0; td < 2; ++td)
        #pragma unroll
        for (int km = 0; km < 5; ++km)
          bfr[td][km] =
              *(const short8*)(vt + (td * 16 + r16) * 160 + km * 32 + quad * 8);

      #pragma unroll
      for (int u = 0; u < 2; ++u) {
        int t = u * 4 + wv;
        if (t < 6) {
          int tn = t >> 1, td = t & 1;
          floatx4 acc = z;
          #pragma unroll
          for (int km = 0; km < 5; ++km) {
            short8 a;
            if (km == 4 && quad >= 2) {
              a = (short8)(short)0;          // P cols 144..159 are zero
            } else {
              const bfu* ap = Ss + (tn * 16 + r16) * 148 + km * 32 + quad * 8;
              *(short4v*)&a       = *(const short4v*)ap;
              *((short4v*)&a + 1) = *(const short4v*)(ap + 4);
            }
            acc = __builtin_amdgcn_mfma_f32_16x16x32_bf16(bfr[td][km], a, acc, 0, 0, 0);
          }
          short4v o;
          #pragma unroll
          for (int i = 0; i < 4; ++i) o[i] = (short)f2bf(acc[i]);
          ov[hh][u] = o;
        }
      }
      __syncthreads();   // PV reads of Ss done before overwrite
    }

    // stage O chunk [48][64] (both heads) in Ss, store full 128B lines
    #pragma unroll
    for (int hh = 0; hh < 2; ++hh)
      #pragma unroll
      for (int u = 0; u < 2; ++u) {
        int t = u * 4 + wv;
        if (t < 6) {
          int tn = t >> 1, td = t & 1;
          int ro = tn * 16 + r16;
          *(short4v*)(Ss + ro * 80 + hh * 32 + td * 16 + quad * 4) = ov[hh][u];
        }
      }
    __syncthreads();
    #pragma unroll
    for (int u = 0; u < 2; ++u) {
      int c = u * 256 + tid;
      if (c < 384) {                 // 48 rows x 8 chunks of 16B
        int r = c >> 3, k = c & 7;
        *(short8*)(aout + obase + (size_t)(qc * 48 + r) * 192 + k * 8) =
            *(const short8*)(Ss + r * 80 + k * 8);
      }
    }
    if (qc < 2) __syncthreads();     // store reads done before next chunk
  }
}

// ---------------------------------------------------------------------------
extern "C" void kernel_launch(void* const* d_in, const int* in_sizes, int n_in,
                              void* d_out, int out_size, void* d_ws, size_t ws_size,
                              hipStream_t stream) {
  (void)in_sizes; (void)n_in; (void)out_size; (void)ws_size;
  const float* x     = (const float*)d_in[0];
  const float* n1g   = (const float*)d_in[1];
  const float* n1b   = (const float*)d_in[2];
  const float* qkvw  = (const float*)d_in[3];
  const float* qkvb  = (const float*)d_in[4];
  const float* tbl   = (const float*)d_in[5];
  const float* projw = (const float*)d_in[6];
  const float* projb = (const float*)d_in[7];
  const float* n2g   = (const float*)d_in[8];
  const float* n2b   = (const float*)d_in[9];
  const float* fc1w  = (const float*)d_in[10];
  const float* fc1b  = (const float*)d_in[11];
  const float* fc2w  = (const float*)d_in[12];
  const float* fc2b  = (const float*)d_in[13];

  char* ws = (char*)d_ws;
  // ws layout (bytes); peak ~282 MB (hb reuses q/k/v region)
  bfu* wt_qkv   = (bfu*)(ws + 0);          //  576x192
  bfu* wt_proj  = (bfu*)(ws + 221184);     //  192x192
  bfu* wt_fc1   = (bfu*)(ws + 294912);     //  768x192
  bfu* wt_fc2   = (bfu*)(ws + 589824);     //  192x768
  bfu* tblT     = (bfu*)(ws + 884736);     //  compact bias 6*64*3312 bf16
  bfu* A1       = (bfu*)(ws + 16809984);   //  138240x192  (A1 / attn_out / y2)
  bfu* qb       = (bfu*)(ws + 69894144);   //  q [5760][144][32]
  bfu* kb       = (bfu*)(ws + 122978304);  //  k [5760][144][32]
  bfu* vb       = (bfu*)(ws + 176062464);  //  v^T [5760][32][160]
  bfu* hb       = qb;                      //  h reuses q/k/v (138240x768)
  float* out    = (float*)d_out;           //  doubles as x1 buffer

  wt_kernel<<<432, 256, 0, stream>>>(qkvw, wt_qkv, 192, 576);
  wt_kernel<<<144, 256, 0, stream>>>(projw, wt_proj, 192, 192);
  wt_kernel<<<576, 256, 0, stream>>>(fc1w, wt_fc1, 192, 768);
  wt_kernel<<<576, 256, 0, stream>>>(fc2w, wt_fc2, 768, 192);
  bias2_kernel<<<4968, 256, 0, stream>>>(tbl, tblT);
  vpad_kernel<<<5760, 256, 0, stream>>>((unsigned int*)vb);
  ln1_kernel<<<34560, 256, 0, stream>>>(x, n1g, n1b, A1);
  gemm_kernel<<<6480, 256, 0, stream>>>(A1, wt_qkv, qkvb, 192, 6, 0,
                                        nullptr, qb, kb, vb);
  attn_kernel<<<dim3(64, 3, 15), 256, 0, stream>>>(qb, kb, vb, tblT, A1);
  gemm_kernel<<<2160, 256, 0, stream>>>(A1, wt_proj, projb, 192, 2, 1,
                                        x, out, nullptr, nullptr);
  ln2_kernel<<<34560, 256, 0, stream>>>(out, n2g, n2b, A1);
  gemm_kernel<<<8640, 256, 0, stream>>>(A1, wt_fc1, fc1b, 192, 8, 2,
                                        nullptr, hb, nullptr, nullptr);
  gemm_kernel<<<2160, 256, 0, stream>>>(hb, wt_fc2, fc2b, 768, 2, 3,
                                        out, out, nullptr, nullptr);
}

// Round 11
// 908.587 us; speedup vs baseline: 1.0973x; 1.0973x over previous
//
#include <hip/hip_runtime.h>

// ---------------------------------------------------------------------------
// Earth-specific transformer block (Pangu/swin style) for MI355X gfx950.
// DIM=192, HEADS=6 (d=32), RES=(8,96,180), WIN=(2,6,12), SHIFT=(1,3,6), MLP=4x
// All GEMMs in bf16 MFMA (16x16x32), fp32 accumulate. Output fp32.
// R11: COMPOSITION of measured-best halves — GEMM = R7-exact (BK=64 A+B
//      global_load_lds staging, 28KB, XCD-chunked M-major swizzle; verified
//      fastest in R7/R10), attn = R9-exact (full 144-row tile, reg-hoisted
//      phase-1 frags, exp2 no-max softmax, LDS full-line O stores; 197us in
//      R9). R10's Q-chunked attn regressed (3x phase-structure tripled
//      parasitic WRITE 282->731MB) and is reverted.
// ---------------------------------------------------------------------------

typedef __attribute__((ext_vector_type(8))) short short8;
typedef __attribute__((ext_vector_type(4))) short short4v;
typedef __attribute__((ext_vector_type(4))) float floatx4;
typedef unsigned short bfu;   // raw bf16 bits

#define GLOAD_LDS16(g, l)                                            \
  __builtin_amdgcn_global_load_lds(                                  \
      (const __attribute__((address_space(1))) unsigned int*)(g),    \
      (__attribute__((address_space(3))) unsigned int*)(l), 16, 0, 0)

__device__ __forceinline__ bfu f2bf(float f) {
  unsigned int u = __builtin_bit_cast(unsigned int, f);
  u += 0x7fffu + ((u >> 16) & 1u);        // round-to-nearest-even
  return (bfu)(u >> 16);
}
__device__ __forceinline__ float bf2f(bfu s) {
  return __builtin_bit_cast(float, (unsigned int)s << 16);
}

// --- transpose fp32 (K x N) -> bf16 (N x K) --------------------------------
__global__ void wt_kernel(const float* __restrict__ src, bfu* __restrict__ dst,
                          int K, int N) {
  int idx = blockIdx.x * 256 + threadIdx.x;
  if (idx >= K * N) return;
  int k = idx / N, n = idx % N;
  dst[(size_t)n * K + k] = f2bf(src[idx]);
}

// --- compact bias: tblT[h][w][3312] bf16 from table[ep][w][h] fp32 ---------
// Scaled by 1/ln2: softmax computed in exp2 domain.
__global__ void bias2_kernel(const float* __restrict__ table,
                             bfu* __restrict__ out) {
  int idx = blockIdx.x * 256 + threadIdx.x;
  if (idx >= 1271808) return;                    // 6*64*3312
  int h = idx / 211968;
  int r = idx % 211968;
  int w = r / 3312, ep = r % 3312;
  out[idx] = f2bf(table[(size_t)ep * 384 + w * 6 + h] * 1.4426950408889634f);
}

// --- zero the m=144..159 pad columns of the transposed V buffer ------------
__global__ void vpad_kernel(unsigned int* __restrict__ vbw) {
  int tid = threadIdx.x;
  int dd = tid >> 3, c = tid & 7;
  vbw[(size_t)blockIdx.x * 2560 + dd * 80 + 72 + c] = 0;
}

// --- LN1 + roll(-shift) + window-partition gather -> bf16 A1 ---------------
__global__ __launch_bounds__(256) void ln1_kernel(
    const float* __restrict__ x, const float* __restrict__ g,
    const float* __restrict__ be, bfu* __restrict__ A1) {
  int wv = threadIdx.x >> 6, lane = threadIdx.x & 63;
  int r = blockIdx.x * 4 + wv;
  int n = r % 144, w = (r / 144) & 63, bb = r / 9216;
  int ip = w >> 4, il = w & 15;
  int p1 = n / 72, rem = n % 72, l1 = rem / 12, o1 = rem % 12;
  int pl = ip * 2 + p1 + 1;   if (pl >= 8) pl -= 8;     // rolled pos + shift
  int lat = il * 6 + l1 + 3;  if (lat >= 96) lat -= 96;
  int lon = bb * 12 + o1 + 6; if (lon >= 180) lon -= 180;
  size_t t = (size_t)(pl * 96 + lat) * 180 + lon;
  const float* xr = x + t * 192;
  float v0 = xr[lane], v1 = xr[lane + 64], v2 = xr[lane + 128];
  float s = v0 + v1 + v2;
  #pragma unroll
  for (int o = 32; o; o >>= 1) s += __shfl_xor(s, o);
  float mu = s * (1.0f / 192.0f);
  float d0 = v0 - mu, d1 = v1 - mu, d2 = v2 - mu;
  float q2 = d0 * d0 + d1 * d1 + d2 * d2;
  #pragma unroll
  for (int o = 32; o; o >>= 1) q2 += __shfl_xor(q2, o);
  float rstd = rsqrtf(q2 * (1.0f / 192.0f) + 1e-5f);
  bfu* orow = A1 + (size_t)r * 192;
  orow[lane]       = f2bf(d0 * rstd * g[lane]       + be[lane]);
  orow[lane + 64]  = f2bf(d1 * rstd * g[lane + 64]  + be[lane + 64]);
  orow[lane + 128] = f2bf(d2 * rstd * g[lane + 128] + be[lane + 128]);
}

// --- LN2 (natural rows) -> bf16 --------------------------------------------
__global__ __launch_bounds__(256) void ln2_kernel(
    const float* __restrict__ xin, const float* __restrict__ g,
    const float* __restrict__ be, bfu* __restrict__ yout) {
  int wv = threadIdx.x >> 6, lane = threadIdx.x & 63;
  size_t r = (size_t)blockIdx.x * 4 + wv;
  const float* xr = xin + r * 192;
  float v0 = xr[lane], v1 = xr[lane + 64], v2 = xr[lane + 128];
  float s = v0 + v1 + v2;
  #pragma unroll
  for (int o = 32; o; o >>= 1) s += __shfl_xor(s, o);
  float mu = s * (1.0f / 192.0f);
  float d0 = v0 - mu, d1 = v1 - mu, d2 = v2 - mu;
  float q2 = d0 * d0 + d1 * d1 + d2 * d2;
  #pragma unroll
  for (int o = 32; o; o >>= 1) q2 += __shfl_xor(q2, o);
  float rstd = rsqrtf(q2 * (1.0f / 192.0f) + 1e-5f);
  bfu* orow = yout + r * 192;
  orow[lane]       = f2bf(d0 * rstd * g[lane]       + be[lane]);
  orow[lane + 64]  = f2bf(d1 * rstd * g[lane + 64]  + be[lane + 64]);
  orow[lane + 128] = f2bf(d2 * rstd * g[lane + 128] + be[lane + 128]);
}

// --- MFMA GEMM: one (128-row M-panel, 96-col N-tile) per block -------------
// (R7-exact) grid = 1080*NT blocks, XCD-chunked M-major swizzle. BK=64:
// A (128x64) + B (96x64) async-staged to LDS via global_load_lds(16B),
// XOR slot swizzle, 2 barriers per chunk. LDS 28 KB.
__global__ __launch_bounds__(256, 4) void gemm_kernel(
    const bfu* __restrict__ A, const bfu* __restrict__ BT,
    const float* __restrict__ bias, int K, int NT, int mode,
    const float* aux, void* out0, void* out1, void* out2) {
  __shared__ __align__(16) short LB[14336];      // 28 KB: As[8192] + Bs[6144]
  short* As = LB;                                // [128][8 slots of 8 shorts]
  short* Bs = LB + 8192;                         // [96][8 slots]
  bfu* E = (bfu*)LB;                             // epilogue tile [128][104]
  const int tid = threadIdx.x;
  const int wv = tid >> 6, lane = tid & 63;
  const int r16 = lane & 15, quad = lane >> 4;
  const int sw = r16 & 7;                        // read-side XOR key

  const int W = gridDim.x;
  const int work = (blockIdx.x & 7) * (W >> 3) + (blockIdx.x >> 3);
  const int m0 = (work / NT) * 128;
  const int n0 = (work % NT) * 96;
  const bfu* Bsrc = BT + (size_t)n0 * K;

  floatx4 acc[2][6];
  #pragma unroll
  for (int s = 0; s < 2; ++s)
    #pragma unroll
    for (int j = 0; j < 6; ++j) acc[s][j] = (floatx4){0.f, 0.f, 0.f, 0.f};

  for (int kc = 0; kc < K; kc += 64) {
    __syncthreads();                           // prev chunk fully read
    // stage A: 1024 16B-chunks (128 rows x 8 slots), 4 per thread
    #pragma unroll
    for (int j = 0; j < 4; ++j) {
      int c = j * 256 + tid;
      int row = c >> 3, l = (c & 7) ^ (row & 7);
      GLOAD_LDS16(A + (size_t)(m0 + row) * K + kc + l * 8, As + c * 8);
    }
    // stage B: 768 16B-chunks (96 rows x 8 slots), 3 per thread
    #pragma unroll
    for (int j = 0; j < 3; ++j) {
      int c = j * 256 + tid;
      int row = c >> 3, l = (c & 7) ^ (row & 7);
      GLOAD_LDS16(Bsrc + (size_t)row * K + kc + l * 8, Bs + c * 8);
    }
    __syncthreads();                           // drains vmcnt -> data ready
    #pragma unroll
    for (int ks = 0; ks < 2; ++ks) {
      const int p8 = ((ks * 4 + quad) ^ sw) * 8;
      short8 a[2], b[6];
      #pragma unroll
      for (int s = 0; s < 2; ++s)
        a[s] = *(const short8*)(As + (wv * 32 + s * 16 + r16) * 64 + p8);
      #pragma unroll
      for (int j = 0; j < 6; ++j)
        b[j] = *(const short8*)(Bs + (j * 16 + r16) * 64 + p8);
      #pragma unroll
      for (int s = 0; s < 2; ++s)
        #pragma unroll
        for (int j = 0; j < 6; ++j)
          acc[s][j] =
              __builtin_amdgcn_mfma_f32_16x16x32_bf16(a[s], b[j], acc[s][j], 0, 0, 0);
    }
  }

  if (mode == 0 || mode == 2) {
    // ---- stage epilogue tile in LDS (bf16), then coalesced 16B stores ----
    __syncthreads();                 // all waves done reading As/Bs
    #pragma unroll
    for (int s = 0; s < 2; ++s) {
      int er = wv * 32 + s * 16 + quad * 4;
      #pragma unroll
      for (int j = 0; j < 6; ++j) {
        int c = j * 16 + r16;
        float bia = bias[n0 + c];
        #pragma unroll
        for (int i = 0; i < 4; ++i) {
          float val = acc[s][j][i] + bia;
          if (mode == 0) {
            // q pre-scale: d^-0.5 * 1/ln2 (softmax in exp2 domain)
            if (n0 < 192) val *= 0.25503633958871686f;
            E[(er + i) * 104 + c] = f2bf(val);
          } else {
            float ge = 0.5f * val * (1.0f + erff(val * 0.70710678118654752f));
            E[(er + i) * 104 + c] = f2bf(ge);
          }
        }
      }
    }
    __syncthreads();
    if (mode == 2) {
      // h[row][768], 16B chunks: 128 rows x 12 chunks = 1536
      #pragma unroll
      for (int u = 0; u < 6; ++u) {
        int id = u * 256 + tid;
        int r = id / 12, c8 = (id % 12) * 8;
        *(short8*)((bfu*)out0 + (size_t)(m0 + r) * 768 + n0 + c8) =
            *(const short8*)(E + r * 104 + c8);
      }
    } else if (n0 < 384) {
      // q or k: [win][n][32], 16B chunks along dd
      bfu* dst = (bfu*)(n0 < 192 ? out0 : out1);
      #pragma unroll
      for (int u = 0; u < 6; ++u) {
        int id = u * 256 + tid;
        int r = id / 12, c8 = (id % 12) * 8;
        int row = m0 + r;
        int n = row % 144, w = (row / 144) & 63, bb = row / 9216;
        int head = ((n0 + c8) % 192) >> 5, dd = c8 & 31;
        size_t win = (size_t)(bb * 6 + head) * 64 + w;
        *(short8*)(dst + win * 4608 + n * 32 + dd) =
            *(const short8*)(E + r * 104 + c8);
      }
    } else {
      // v transposed: [win][dd][160], 16B chunks along n (8 rows of E)
      #pragma unroll
      for (int u = 0; u < 6; ++u) {
        int id = u * 256 + tid;
        int c = id % 96, k8 = id / 96;
        int r0 = k8 * 8;
        int row0 = m0 + r0;                // multiples of 8; 144%8==0
        int n = row0 % 144, w = (row0 / 144) & 63, bb = row0 / 9216;
        int head = ((n0 + c) % 192) >> 5, dd = c & 31;
        size_t win = (size_t)(bb * 6 + head) * 64 + w;
        short8 t8;
        #pragma unroll
        for (int i = 0; i < 8; ++i) t8[i] = (short)E[(r0 + i) * 104 + c];
        *(short8*)((bfu*)out2 + win * 5120 + dd * 160 + n) = t8;
      }
    }
  } else {
    // ---- direct fp32 epilogue (modes 1 and 3): 64B quad-chunk stores ----
    #pragma unroll
    for (int s = 0; s < 2; ++s) {
      const int row0 = m0 + wv * 32 + s * 16 + quad * 4;
      #pragma unroll
      for (int j = 0; j < 6; ++j) {
        int col = n0 + j * 16 + r16;
        float bia = bias[col];
        #pragma unroll
        for (int i = 0; i < 4; ++i) {
          int row = row0 + i;
          float val = acc[s][j][i] + bia;
          if (mode == 1) {
            int n = row % 144, w = (row / 144) & 63, bb = row / 9216;
            int ip = w >> 4, il = w & 15;
            int p1 = n / 72, rem = n % 72, l1 = rem / 12, o1 = rem % 12;
            int pl = ip * 2 + p1 + 1;   if (pl >= 8) pl -= 8;
            int lat = il * 6 + l1 + 3;  if (lat >= 96) lat -= 96;
            int lon = bb * 12 + o1 + 6; if (lon >= 180) lon -= 180;
            size_t t = (size_t)(pl * 96 + lat) * 180 + lon;
            ((float*)out0)[t * 192 + col] = aux[t * 192 + col] + val;
          } else {
            size_t idx = (size_t)row * 192 + col;
            ((float*)out0)[idx] = aux[idx] + val;
          }
        }
      }
    }
  }
}

// --- windowed attention: one block per (b, head-pair, w) --------------------
// (R9-exact) phase-1 frags register-hoisted (qf[9] full-unrolled, per-wave
// k-frags in named regs; wave wv owns cols tm={2wv,2wv+1} and tm=8 for
// tn%4==wv). Softmax: no max pass, exp2 domain (Q/bias pre-scaled by 1/ln2),
// per-lane col-invariants hoisted. Output staged in LDS, full-line stores.
__global__ __launch_bounds__(256) void attn_kernel(
    const bfu* __restrict__ qg_, const bfu* __restrict__ kg_,
    const bfu* __restrict__ vg_, const bfu* __restrict__ tblT,
    bfu* __restrict__ aout) {
  __shared__ __align__(16) bfu Ss[144 * 148];   // 42.6 KB
  __shared__ __align__(16) bfu bias_l[3312];    // 6.6 KB slice
  __shared__ unsigned short rn[144];            // row bias index part
  __shared__ short cm[144];                     // col bias index part
  __shared__ unsigned char regs[144];           // shift-mask region ids

  const int w = blockIdx.x, h0 = blockIdx.y * 2, b = blockIdx.z;
  const int tid = threadIdx.x;
  const int wv = tid >> 6, lane = tid & 63, r16 = lane & 15, quad = lane >> 4;

  if (tid < 144) {
    int n = tid;
    int p1 = n / 72, rem = n % 72, l1 = rem / 12, o1 = rem % 12;
    rn[n] = (unsigned short)(828 * p1 + 23 * l1 + o1 + 11);
    cm[n] = (short)(1656 * p1 + 138 * l1 - o1);
    int ip = w >> 4, il = w & 15;
    int pl = ip * 2 + p1, lat = il * 6 + l1, lon = b * 12 + o1;
    int rp = pl < 6 ? 0 : (pl < 7 ? 1 : 2);
    int rl = lat < 90 ? 0 : (lat < 93 ? 1 : 2);
    int ro = lon < 174 ? 0 : 1;
    regs[n] = (unsigned char)(rp * 9 + rl * 3 + ro);
  }

  // async-stage bias slice for head h0 (414 x 16B chunks)
  {
    const bfu* bsrc = tblT + (size_t)(h0 * 64 + w) * 3312;
    GLOAD_LDS16(bsrc + tid * 8, bias_l + tid * 8);
    if (tid < 158) GLOAD_LDS16(bsrc + (256 + tid) * 8, bias_l + (256 + tid) * 8);
  }
  __syncthreads();                 // tables visible (also drains bias load)

  // per-lane column invariants (cols c = r16 + 16j, fixed for the block)
  short cmv[9];
  unsigned char creg[9];
  #pragma unroll
  for (int j = 0; j < 9; ++j) {
    int c = r16 + 16 * j;
    cmv[j] = cm[c];
    creg[j] = regs[c];
  }

  short4v ov[2][5];
  #pragma unroll
  for (int hh = 0; hh < 2; ++hh) {
    const int h = h0 + hh;
    const size_t win = (size_t)((b * 6 + h) * 64 + w);
    const bfu* qg = qg_ + win * 4608;
    const bfu* kg = kg_ + win * 4608;
    const bfu* vt = vg_ + win * 5120;

    // Phase 1: S = Q K^T. All 9 q-frags + this wave's 3 k-frags hoisted.
    short8 qf[9];
    #pragma unroll
    for (int t9 = 0; t9 < 9; ++t9)
      qf[t9] = *(const short8*)(qg + (t9 * 16 + r16) * 32 + quad * 8);
    const int tma = wv * 2, tmb = wv * 2 + 1;
    short8 kfa = *(const short8*)(kg + (tma * 16 + r16) * 32 + quad * 8);
    short8 kfb = *(const short8*)(kg + (tmb * 16 + r16) * 32 + quad * 8);
    short8 kfc = *(const short8*)(kg + (128 + r16) * 32 + quad * 8);
    const floatx4 z = (floatx4){0.f, 0.f, 0.f, 0.f};
    #pragma unroll
    for (int tn = 0; tn < 9; ++tn) {
      bfu* srow = Ss + (tn * 16 + quad * 4) * 148;
      floatx4 d = __builtin_amdgcn_mfma_f32_16x16x32_bf16(qf[tn], kfa, z, 0, 0, 0);
      #pragma unroll
      for (int i = 0; i < 4; ++i) srow[i * 148 + tma * 16 + r16] = f2bf(d[i]);
      d = __builtin_amdgcn_mfma_f32_16x16x32_bf16(qf[tn], kfb, z, 0, 0, 0);
      #pragma unroll
      for (int i = 0; i < 4; ++i) srow[i * 148 + tmb * 16 + r16] = f2bf(d[i]);
      if ((tn & 3) == wv) {
        d = __builtin_amdgcn_mfma_f32_16x16x32_bf16(qf[tn], kfc, z, 0, 0, 0);
        #pragma unroll
        for (int i = 0; i < 4; ++i) srow[i * 148 + 128 + r16] = f2bf(d[i]);
      }
    }
    __syncthreads();   // S ready; bias slice loaded

    // Phase 2: softmax in exp2 domain, no max pass.
    for (int rb = 0; rb < 9; ++rb) {
      int rr = rb * 16 + wv * 4 + quad;
      unsigned char rgn = regs[rr];
      int rnv = rn[rr];
      const bfu* srow = Ss + rr * 148;
      float v[9];
      float sum = 0.f;
      #pragma unroll
      for (int j = 0; j < 9; ++j) {
        float s = bf2f(srow[r16 + 16 * j]) + bf2f(bias_l[rnv + cmv[j]]);
        s = (creg[j] != rgn) ? s - 144.26950408889634f : s;
        v[j] = exp2f(s);
        sum += v[j];
      }
      #pragma unroll
      for (int o = 8; o; o >>= 1) sum += __shfl_xor(sum, o);
      float inv = 1.0f / sum;
      bfu* wrow = Ss + rr * 148;
      #pragma unroll
      for (int j = 0; j < 9; ++j) wrow[r16 + 16 * j] = f2bf(v[j] * inv);
    }
    __syncthreads();   // P ready; bias_l reads done

    if (hh == 0) {     // overlap next head's bias load with PV
      const bfu* bsrc = tblT + (size_t)((h0 + 1) * 64 + w) * 3312;
      GLOAD_LDS16(bsrc + tid * 8, bias_l + tid * 8);
      if (tid < 158) GLOAD_LDS16(bsrc + (256 + tid) * 8, bias_l + (256 + tid) * 8);
    }

    // Phase 3: O = P V, operand-swapped; V^T B-frags hoisted.
    short8 bfr[2][5];
    #pragma unroll
    for (int td = 0; td < 2; ++td)
      #pragma unroll
      for (int km = 0; km < 5; ++km)
        bfr[td][km] =
            *(const short8*)(vt + (td * 16 + r16) * 160 + km * 32 + quad * 8);

    #pragma unroll
    for (int u = 0; u < 5; ++u) {
      int t = wv * 5 + u;
      if (t < 18) {
        int tn = t >> 1, td = t & 1;
        floatx4 acc = (floatx4){0.f, 0.f, 0.f, 0.f};
        #pragma unroll
        for (int km = 0; km < 5; ++km) {
          short8 a;
          if (km == 4 && quad >= 2) {
            a = (short8)(short)0;          // P cols 144..159 are zero
          } else {
            const bfu* ap = Ss + (tn * 16 + r16) * 148 + km * 32 + quad * 8;
            *(short4v*)&a       = *(const short4v*)ap;
            *((short4v*)&a + 1) = *(const short4v*)(ap + 4);
          }
          acc = __builtin_amdgcn_mfma_f32_16x16x32_bf16(bfr[td][km], a, acc, 0, 0, 0);
        }
        short4v o;
        #pragma unroll
        for (int i = 0; i < 4; ++i) o[i] = (short)f2bf(acc[i]);
        ov[hh][u] = o;
      }
    }
    if (hh == 0) __syncthreads();   // Ss reads done before next head's phase 1
  }

  // stage O tile [144][64] (both heads) in LDS, store full 128B lines
  __syncthreads();                  // all waves done reading Ss (hh=1 PV)
  bfu* Os = Ss;                     // reuse, stride 80 shorts (160B rows)
  #pragma unroll
  for (int u = 0; u < 5; ++u) {
    int t = wv * 5 + u;
    if (t < 18) {
      int tn = t >> 1, td = t & 1;
      int ro = tn * 16 + r16;
      *(short4v*)(Os + ro * 80 + td * 16 + quad * 4)      = ov[0][u];
      *(short4v*)(Os + ro * 80 + 32 + td * 16 + quad * 4) = ov[1][u];
    }
  }
  __syncthreads();
  const size_t obase = (size_t)((b * 64 + w) * 144) * 192 + h0 * 32;
  #pragma unroll
  for (int u = 0; u < 5; ++u) {
    int c = u * 256 + tid;
    if (c < 1152) {                 // 144 rows x 8 chunks of 16B
      int r = c >> 3, k = c & 7;
      *(short8*)(aout + obase + (size_t)r * 192 + k * 8) =
          *(const short8*)(Os + r * 80 + k * 8);
    }
  }
}

// ---------------------------------------------------------------------------
extern "C" void kernel_launch(void* const* d_in, const int* in_sizes, int n_in,
                              void* d_out, int out_size, void* d_ws, size_t ws_size,
                              hipStream_t stream) {
  (void)in_sizes; (void)n_in; (void)out_size; (void)ws_size;
  const float* x     = (const float*)d_in[0];
  const float* n1g   = (const float*)d_in[1];
  const float* n1b   = (const float*)d_in[2];
  const float* qkvw  = (const float*)d_in[3];
  const float* qkvb  = (const float*)d_in[4];
  const float* tbl   = (const float*)d_in[5];
  const float* projw = (const float*)d_in[6];
  const float* projb = (const float*)d_in[7];
  const float* n2g   = (const float*)d_in[8];
  const float* n2b   = (const float*)d_in[9];
  const float* fc1w  = (const float*)d_in[10];
  const float* fc1b  = (const float*)d_in[11];
  const float* fc2w  = (const float*)d_in[12];
  const float* fc2b  = (const float*)d_in[13];

  char* ws = (char*)d_ws;
  // ws layout (bytes); peak ~282 MB (hb reuses q/k/v region)
  bfu* wt_qkv   = (bfu*)(ws + 0);          //  576x192
  bfu* wt_proj  = (bfu*)(ws + 221184);     //  192x192
  bfu* wt_fc1   = (bfu*)(ws + 294912);     //  768x192
  bfu* wt_fc2   = (bfu*)(ws + 589824);     //  192x768
  bfu* tblT     = (bfu*)(ws + 884736);     //  compact bias 6*64*3312 bf16
  bfu* A1       = (bfu*)(ws + 16809984);   //  138240x192  (A1 / attn_out / y2)
  bfu* qb       = (bfu*)(ws + 69894144);   //  q [5760][144][32]
  bfu* kb       = (bfu*)(ws + 122978304);  //  k [5760][144][32]
  bfu* vb       = (bfu*)(ws + 176062464);  //  v^T [5760][32][160]
  bfu* hb       = qb;                      //  h reuses q/k/v (138240x768)
  float* out    = (float*)d_out;           //  doubles as x1 buffer

  wt_kernel<<<432, 256, 0, stream>>>(qkvw, wt_qkv, 192, 576);
  wt_kernel<<<144, 256, 0, stream>>>(projw, wt_proj, 192, 192);
  wt_kernel<<<576, 256, 0, stream>>>(fc1w, wt_fc1, 192, 768);
  wt_kernel<<<576, 256, 0, stream>>>(fc2w, wt_fc2, 768, 192);
  bias2_kernel<<<4968, 256, 0, stream>>>(tbl, tblT);
  vpad_kernel<<<5760, 256, 0, stream>>>((unsigned int*)vb);
  ln1_kernel<<<34560, 256, 0, stream>>>(x, n1g, n1b, A1);
  gemm_kernel<<<6480, 256, 0, stream>>>(A1, wt_qkv, qkvb, 192, 6, 0,
                                        nullptr, qb, kb, vb);
  attn_kernel<<<dim3(64, 3, 15), 256, 0, stream>>>(qb, kb, vb, tblT, A1);
  gemm_kernel<<<2160, 256, 0, stream>>>(A1, wt_proj, projb, 192, 2, 1,
                                        x, out, nullptr, nullptr);
  ln2_kernel<<<34560, 256, 0, stream>>>(out, n2g, n2b, A1);
  gemm_kernel<<<8640, 256, 0, stream>>>(A1, wt_fc1, fc1b, 192, 8, 2,
                                        nullptr, hb, nullptr, nullptr);
  gemm_kernel<<<2160, 256, 0, stream>>>(hb, wt_fc2, fc2b, 768, 2, 3,
                                        out, out, nullptr, nullptr);
}